// Round 4
// baseline (241.344 us; speedup 1.0000x reference)
//
#include <hip/hip_runtime.h>

// All-pole time-varying IIR via chunked affine-state decomposition.
// y[t] = K[t]*x[t] - sum_m A[t][m]*y[t-1-m], coeffs lin-interp per 80-sample frame.
// Chunks of LCHUNK samples; per chunk the state map is affine (M_c, f_c).
// phase1: 31 lane-runs/chunk build M_c,f_c.           (VALU-bound, bulk of work)
// phase2a: compose 5-chunk segment maps (LDS-staged). (parallel)
// phase2b: per-batch scan of segment maps.            (tiny serial)
// phase2c: expand per-chunk start states in segment.  (parallel)
// phase3: exact per-chunk re-run from known state.    (parallel)
// Rules learned: all local-array indices compile-time static (rule #20);
// phase1 live-set must fit the 128-VGPR granule (round-3: 84+spill = 45% VALUBusy).

#define Bb 64
#define Tt 16000
#define Nn 200
#define Pp 80
#define Mm 30
#define Dd 31
#define Gseg 5

__device__ __forceinline__ void load_coeffs(const float* __restrict__ p0,
                                            const float* __restrict__ p1,
                                            float (&c0)[Mm], float (&dc)[Mm],
                                            float& K0, float& dK) {
  K0 = p0[0];
  dK = p1[0] - K0;
#pragma unroll
  for (int m = 0; m < Mm; ++m) {
    float v0 = p0[m + 1];
    c0[m] = v0;
    dc[m] = p1[m + 1] - v0;
  }
}

// ---------------- Phase 1 ----------------
template <int LCHUNK>
__global__ __launch_bounds__(256, 4) void phase1(const float* __restrict__ x,
                                                 const float* __restrict__ a,
                                                 float* __restrict__ Mf) {
  constexpr int C = Tt / LCHUNK;
  constexpr int NBLK = LCHUNK / 4;
  constexpr int FRAMES = LCHUNK / Pp;
  const int tid = threadIdx.x;
  const int wave = tid >> 6, lane = tid & 63, half = lane >> 5, role = lane & 31;
  const int ch = ((blockIdx.x * 4 + wave) << 1) + half;
  const int b = ch / C, c = ch % C;

  float hh[34];
#pragma unroll
  for (int i = 0; i < 34; ++i) hh[i] = (i < Mm && role == (29 - i)) ? 1.0f : 0.0f;
  const float gmask = (role == 30) ? 1.f : 0.f;

  const int n0 = c * FRAMES;
  const float* arow = a + ((size_t)b * Nn + n0) * Dd;
  const float* arow1 = (n0 + 1 < Nn) ? arow + Dd : arow;
  float c0[Mm], dc[Mm], K0, dK;
  load_coeffs(arow, arow1, c0, dc, K0, dK);

  const float* xp = x + (size_t)b * Tt + c * LCHUNK;
  const float finc = 1.0f / Pp;
  float fbase = 0.f;

#pragma unroll 1
  for (int blk = 0; blk < NBLK; ++blk) {
    if constexpr (FRAMES == 2) {
      if (blk == NBLK / 2) {
        const int n = n0 + 1;
        const float* p0 = a + ((size_t)b * Nn + n) * Dd;
        const float* p1 = (n + 1 < Nn) ? (p0 + Dd) : p0;
        load_coeffs(p0, p1, c0, dc, K0, dK);
        fbase = 0.f;
      }
    }
    const float4 xq = *reinterpret_cast<const float4*>(xp + blk * 4);
#pragma unroll
    for (int k = 0; k < 4; ++k) {
      float a0 = 0.f, a1 = 0.f, d0 = 0.f, d1 = 0.f;
#pragma unroll
      for (int m = 0; m < Mm; m += 2) {
        float h0 = hh[29 + k - m];
        float h1 = hh[28 + k - m];
        a0 = fmaf(c0[m], h0, a0);
        d0 = fmaf(dc[m], h0, d0);
        a1 = fmaf(c0[m + 1], h1, a1);
        d1 = fmaf(dc[m + 1], h1, d1);
      }
      const float f = fmaf((float)k, finc, fbase);
      const float Kt = fmaf(dK, f, K0);
      const float xk = (k == 0) ? xq.x : (k == 1) ? xq.y : (k == 2) ? xq.z : xq.w;
      const float inp = gmask * (Kt * xk);
      const float y = fmaf(-f, d0 + d1, inp - (a0 + a1));
      hh[30 + k] = y;
    }
#pragma unroll
    for (int i = 0; i < 30; ++i) hh[i] = hh[i + 4];
    fbase += 4.0f * finc;
  }

  if (role <= 30) {
    float* dst = Mf + ((size_t)ch * 31 + role) * Mm;
#pragma unroll
    for (int m = 0; m < Mm; ++m) dst[m] = hh[29 - m];
  }
}

// ---------------- Phase 2a: segment map composition ----------------
template <int C, int S>
__global__ __launch_bounds__(64) void phase2a(const float* __restrict__ Mf,
                                              float* __restrict__ Mseg) {
  const int blk = blockIdx.x;  // b*(S/2) + q
  const int b = blk / (S / 2);
  const int q = blk % (S / 2);
  const int lane = threadIdx.x;
  const int h = lane >> 5, role = lane & 31;
  const int seg = 2 * q + h;

  __shared__ float lds[2 * Gseg * 930];
  const size_t base = ((size_t)b * C + (size_t)(2 * q) * Gseg) * 930;
  {
    const float2* src = reinterpret_cast<const float2*>(Mf + base);
    float2* d2 = reinterpret_cast<float2*>(lds);
    for (int i = lane; i < Gseg * 930; i += 64) d2[i] = src[i];
  }
  __syncthreads();

  float st[30];
#pragma unroll
  for (int i = 0; i < 30; ++i) st[i] = (role == i) ? 1.f : 0.f;
  const float fmask = (role == 30) ? 1.f : 0.f;

  const int off0 = h * (Gseg * 930);
#pragma unroll 1
  for (int g = 0; g < Gseg; ++g) {
    const int off = off0 + g * 930;
    float nst[30];
#pragma unroll
    for (int i = 0; i < 30; ++i) nst[i] = fmask * lds[off + 900 + i];
#pragma unroll
    for (int k = 0; k < 30; ++k) {
      const float sk = st[k];
#pragma unroll
      for (int i = 0; i < 30; ++i) nst[i] = fmaf(lds[off + k * 30 + i], sk, nst[i]);
    }
#pragma unroll
    for (int i = 0; i < 30; ++i) st[i] = nst[i];
  }

  if (role <= 30) {
    float* out = Mseg + ((size_t)(b * S + seg) * 31 + role) * 30;
#pragma unroll
    for (int m = 0; m < 30; ++m) out[m] = st[m];
  }
}

// ---------------- Phase 2b: scan segment maps per batch ----------------
__device__ __forceinline__ void seg_load(const float* __restrict__ M, int idx, int lane,
                                         float (&R)[Dd]) {
  const float* nb = M + (size_t)idx * (31 * 30);
  if (lane < Mm) {
#pragma unroll
    for (int j = 0; j < Dd; ++j) R[j] = nb[j * 30 + lane];
  }
}

__device__ __forceinline__ float seg_step(float s, const float (&R)[Dd]) {
  float a0 = R[Mm], a1 = 0.f;
#pragma unroll
  for (int j = 0; j < Mm; j += 2) {
    a0 = fmaf(R[j], __shfl(s, j, 64), a0);
    a1 = fmaf(R[j + 1], __shfl(s, j + 1, 64), a1);
  }
  return a0 + a1;
}

template <int S>
__global__ __launch_bounds__(64) void phase2b(const float* __restrict__ Mseg,
                                              float* __restrict__ Sseg) {
  const int b = blockIdx.x, lane = threadIdx.x;
  float s = 0.f;
  float RA[Dd], RB[Dd];
  seg_load(Mseg, b * S + 0, lane, RA);
#pragma unroll 1
  for (int seg = 0; seg < S; seg += 2) {
    seg_load(Mseg, b * S + seg + 1, lane, RB);
    if (lane < Mm) Sseg[((size_t)b * S + seg) * 30 + lane] = s;
    s = seg_step(s, RA);
    if (seg + 2 < S) seg_load(Mseg, b * S + seg + 2, lane, RA);
    if (lane < Mm) Sseg[((size_t)b * S + seg + 1) * 30 + lane] = s;
    s = seg_step(s, RB);
  }
}

// ---------------- Phase 2c: expand per-chunk start states ----------------
template <int C, int S>
__global__ __launch_bounds__(64, 2) void phase2c(const float* __restrict__ Mf,
                                                 const float* __restrict__ Sseg,
                                                 float* __restrict__ Sstart) {
  const int bs = blockIdx.x;  // b*S + seg
  const int b = bs / S, seg = bs % S;
  const int lane = threadIdx.x;
  const int chbase = b * C + seg * Gseg;

  float R[Gseg][Dd];
  if (lane < Mm) {
#pragma unroll
    for (int g = 0; g < Gseg; ++g)
#pragma unroll
      for (int j = 0; j < Dd; ++j)
        R[g][j] = Mf[(size_t)(chbase + g) * 930 + j * 30 + lane];
  }
  float s = (lane < Mm) ? Sseg[(size_t)bs * 30 + lane] : 0.f;
#pragma unroll
  for (int g = 0; g < Gseg; ++g) {
    if (lane < Mm) Sstart[(size_t)(chbase + g) * 30 + lane] = s;
    float a0 = R[g][Mm], a1 = 0.f;
#pragma unroll
    for (int j = 0; j < Mm; j += 2) {
      a0 = fmaf(R[g][j], __shfl(s, j, 64), a0);
      a1 = fmaf(R[g][j + 1], __shfl(s, j + 1, 64), a1);
    }
    s = a0 + a1;
  }
}

// ---------------- Phase 3 ----------------
template <int LCHUNK>
__global__ __launch_bounds__(64, 2) void phase3(const float* __restrict__ x,
                                                const float* __restrict__ a,
                                                const float* __restrict__ Sstart,
                                                float* __restrict__ out) {
  constexpr int C = Tt / LCHUNK;
  constexpr int NBLK = LCHUNK / 4;
  constexpr int FRAMES = LCHUNK / Pp;
  const int ch = blockIdx.x * 64 + threadIdx.x;
  const int b = ch / C, c = ch % C;

  float hh[34];
  const float* sp = Sstart + (size_t)ch * 30;
#pragma unroll
  for (int m = 0; m < Mm; ++m) hh[29 - m] = sp[m];
#pragma unroll
  for (int i = 30; i < 34; ++i) hh[i] = 0.f;

  const int n0 = c * FRAMES;
  const float* arow = a + ((size_t)b * Nn + n0) * Dd;
  const float* arow1 = (n0 + 1 < Nn) ? arow + Dd : arow;
  float c0[Mm], dc[Mm], K0, dK;
  load_coeffs(arow, arow1, c0, dc, K0, dK);

  const float* xp = x + (size_t)b * Tt + c * LCHUNK;
  float* yp = out + (size_t)b * Tt + c * LCHUNK;
  const float finc = 1.0f / Pp;
  float fbase = 0.f;

#pragma unroll 1
  for (int blk = 0; blk < NBLK; ++blk) {
    if constexpr (FRAMES == 2) {
      if (blk == NBLK / 2) {
        const int n = n0 + 1;
        const float* p0 = a + ((size_t)b * Nn + n) * Dd;
        const float* p1 = (n + 1 < Nn) ? (p0 + Dd) : p0;
        load_coeffs(p0, p1, c0, dc, K0, dK);
        fbase = 0.f;
      }
    }
    const float4 xq = *reinterpret_cast<const float4*>(xp + blk * 4);
    float y0, y1, y2, y3;
#pragma unroll
    for (int k = 0; k < 4; ++k) {
      float a0 = 0.f, a1 = 0.f, d0 = 0.f, d1 = 0.f;
#pragma unroll
      for (int m = 0; m < Mm; m += 2) {
        float h0 = hh[29 + k - m];
        float h1 = hh[28 + k - m];
        a0 = fmaf(c0[m], h0, a0);
        d0 = fmaf(dc[m], h0, d0);
        a1 = fmaf(c0[m + 1], h1, a1);
        d1 = fmaf(dc[m + 1], h1, d1);
      }
      const float f = fmaf((float)k, finc, fbase);
      const float Kt = fmaf(dK, f, K0);
      const float xk = (k == 0) ? xq.x : (k == 1) ? xq.y : (k == 2) ? xq.z : xq.w;
      const float y = fmaf(-f, d0 + d1, fmaf(Kt, xk, -(a0 + a1)));
      hh[30 + k] = y;
      if (k == 0) y0 = y;
      else if (k == 1) y1 = y;
      else if (k == 2) y2 = y;
      else y3 = y;
    }
    *reinterpret_cast<float4*>(yp + blk * 4) = make_float4(y0, y1, y2, y3);
#pragma unroll
    for (int i = 0; i < 30; ++i) hh[i] = hh[i + 4];
    fbase += 4.0f * finc;
  }
}

// ---------------- Legacy simple phase2 (ws mid-tier) ----------------
__global__ __launch_bounds__(64, 1) void phase2_simple(const float* __restrict__ Mf,
                                                       float* __restrict__ Sstart) {
  const int b = blockIdx.x, lane = threadIdx.x;
  const int C = 100;
  const int chbase = b * C;
  float s = 0.f;
  float B0[Dd], B1[Dd], B2[Dd], B3[Dd];
  seg_load(Mf, chbase + 0, lane, B0);
  seg_load(Mf, chbase + 1, lane, B1);
  seg_load(Mf, chbase + 2, lane, B2);
  seg_load(Mf, chbase + 3, lane, B3);
#pragma unroll 1
  for (int c = 0; c < C; c += 4) {
    if (lane < Mm) Sstart[(size_t)(chbase + c) * 30 + lane] = s;
    s = seg_step(s, B0);
    if (c + 4 < C) seg_load(Mf, chbase + c + 4, lane, B0);
    if (lane < Mm) Sstart[(size_t)(chbase + c + 1) * 30 + lane] = s;
    s = seg_step(s, B1);
    if (c + 5 < C) seg_load(Mf, chbase + c + 5, lane, B1);
    if (lane < Mm) Sstart[(size_t)(chbase + c + 2) * 30 + lane] = s;
    s = seg_step(s, B2);
    if (c + 6 < C) seg_load(Mf, chbase + c + 6, lane, B2);
    if (lane < Mm) Sstart[(size_t)(chbase + c + 3) * 30 + lane] = s;
    s = seg_step(s, B3);
  }
}

// ---------------- Naive fallback ----------------
__global__ void naive_kernel(const float* __restrict__ x, const float* __restrict__ a,
                             float* __restrict__ out) {
  const int b = blockIdx.x * blockDim.x + threadIdx.x;
  if (b >= Bb) return;
  float h[Mm];
#pragma unroll
  for (int m = 0; m < Mm; ++m) h[m] = 0.f;
  for (int n = 0; n < Nn; ++n) {
    const float* p0 = a + ((size_t)b * Nn + n) * Dd;
    const float* p1 = a + ((size_t)b * Nn + min(n + 1, Nn - 1)) * Dd;
    float c0[Mm], dc[Mm];
#pragma unroll
    for (int m = 0; m < Mm; ++m) {
      float v0 = p0[m + 1];
      c0[m] = v0;
      dc[m] = p1[m + 1] - v0;
    }
    const float K0 = p0[0], dK = p1[0] - K0;
    const float* xp = x + (size_t)b * Tt + n * Pp;
    float* yp = out + (size_t)b * Tt + n * Pp;
    for (int i = 0; i < Pp; ++i) {
      const float f = (float)i * (1.0f / Pp);
      float acc = 0.f;
#pragma unroll
      for (int m = 0; m < Mm; ++m) acc = fmaf(fmaf(dc[m], f, c0[m]), h[m], acc);
      const float y = fmaf(fmaf(dK, f, K0), xp[i], -acc);
      yp[i] = y;
#pragma unroll
      for (int m = Mm - 1; m > 0; --m) h[m] = h[m - 1];
      h[0] = y;
    }
  }
}

extern "C" void kernel_launch(void* const* d_in, const int* in_sizes, int n_in,
                              void* d_out, int out_size, void* d_ws, size_t ws_size,
                              hipStream_t stream) {
  const float* x = (const float*)d_in[0];  // (64,16000) f32
  const float* a = (const float*)d_in[1];  // (64,200,31) f32
  float* out = (float*)d_out;              // (64,16000) f32

  // sizes in floats
  auto needBytes = [](int C, int S, bool hier) -> size_t {
    size_t mf = (size_t)Bb * C * 930, ss = (size_t)Bb * C * 30;
    size_t ms = hier ? (size_t)Bb * S * 930 : 0, sg = hier ? (size_t)Bb * S * 30 : 0;
    return (mf + ss + ms + sg) * 4;
  };

  if (ws_size >= needBytes(200, 40, true)) {
    constexpr int C = 200, S = 40;
    float* Mf = (float*)d_ws;
    float* Sstart = Mf + (size_t)Bb * C * 930;
    float* Mseg = Sstart + (size_t)Bb * C * 30;
    float* Sseg = Mseg + (size_t)Bb * S * 930;
    phase1<80><<<Bb * C / 8, 256, 0, stream>>>(x, a, Mf);
    phase2a<C, S><<<Bb * (S / 2), 64, 0, stream>>>(Mf, Mseg);
    phase2b<S><<<Bb, 64, 0, stream>>>(Mseg, Sseg);
    phase2c<C, S><<<Bb * S, 64, 0, stream>>>(Mf, Sseg, Sstart);
    phase3<80><<<Bb * C / 64, 64, 0, stream>>>(x, a, Sstart, out);
  } else if (ws_size >= needBytes(100, 20, true)) {
    constexpr int C = 100, S = 20;
    float* Mf = (float*)d_ws;
    float* Sstart = Mf + (size_t)Bb * C * 930;
    float* Mseg = Sstart + (size_t)Bb * C * 30;
    float* Sseg = Mseg + (size_t)Bb * S * 930;
    phase1<160><<<Bb * C / 8, 256, 0, stream>>>(x, a, Mf);
    phase2a<C, S><<<Bb * (S / 2), 64, 0, stream>>>(Mf, Mseg);
    phase2b<S><<<Bb, 64, 0, stream>>>(Mseg, Sseg);
    phase2c<C, S><<<Bb * S, 64, 0, stream>>>(Mf, Sseg, Sstart);
    phase3<160><<<Bb * C / 64, 64, 0, stream>>>(x, a, Sstart, out);
  } else if (ws_size >= needBytes(100, 0, false)) {
    constexpr int C = 100;
    float* Mf = (float*)d_ws;
    float* Sstart = Mf + (size_t)Bb * C * 930;
    phase1<160><<<Bb * C / 8, 256, 0, stream>>>(x, a, Mf);
    phase2_simple<<<Bb, 64, 0, stream>>>(Mf, Sstart);
    phase3<160><<<Bb * C / 64, 64, 0, stream>>>(x, a, Sstart, out);
  } else {
    naive_kernel<<<1, 64, 0, stream>>>(x, a, out);
  }
}